// Round 3
// baseline (408.848 us; speedup 1.0000x reference)
//
#include <hip/hip_runtime.h>

#define TB 128

// Wave-synchronous fence: DS ops complete in order within a wave (ISA
// guarantee); this only stops the COMPILER from reordering/caching LDS.
#define WAVE_SYNC() do { asm volatile("" ::: "memory"); \
                         __builtin_amdgcn_wave_barrier(); \
                         asm volatile("" ::: "memory"); } while (0)

// ---------------- LDS layout (float offsets), total 3664 floats = 14.3 KB ----
#define XSP    0        // 16 rows x 196 (spatial-conv out, zero-padded both sides)
// transformer scratch aliases XSP (frontend dead by then):
#define H1     0        // 6 x 20
#define QKV    128      // 6 x 196 (q at +0, k at +64, v at +128 within row)
#define OATT   1312     // 6 x 68
#define MHS    1728     // 6 x 36   (ends 1944 < 3136)
#define POOL   3136     // 16 x 28
#define TOK    3584     // 80
#define LDS_TOT 3664

__device__ __forceinline__ float ln_norm16(float z, float g, float bb) {
    float s = z, q = z * z;
    #pragma unroll
    for (int off = 8; off >= 1; off >>= 1) {
        s += __shfl_xor(s, off, 16);
        q += __shfl_xor(q, off, 16);
    }
    float mean = s * 0.0625f;
    float var  = q * 0.0625f - mean * mean;
    return (z - mean) * rsqrtf(var + 1e-5f) * g + bb;
}

__device__ __forceinline__ float gelu_exact(float a) {
    float xa = fabsf(a) * 0.70710678118654752f;
    float tt = 1.f / (1.f + 0.3275911f * xa);
    float poly = tt * (0.254829592f + tt * (-0.284496736f + tt * (1.421413741f
               + tt * (-1.453152027f + tt * 1.061405429f))));
    float erfv = 1.f - poly * __expf(-xa * xa);
    erfv = a >= 0.f ? erfv : -erfv;
    return 0.5f * a * (1.f + erfv);
}

__device__ __forceinline__ float dot16(const float* h, float4 w0, float4 w1,
                                       float4 w2, float4 w3) {
    return h[0]*w0.x + h[1]*w0.y + h[2]*w0.z + h[3]*w0.w
         + h[4]*w1.x + h[5]*w1.y + h[6]*w1.z + h[7]*w1.w
         + h[8]*w2.x + h[9]*w2.y + h[10]*w2.z + h[11]*w2.w
         + h[12]*w3.x + h[13]*w3.y + h[14]*w3.z + h[15]*w3.w;
}

extern "C" __global__ __launch_bounds__(TB, 4)
void eegnet_vit_fused(
    const float* __restrict__ x,
    const float* __restrict__ conv_t_w, const float* __restrict__ conv_t_b,
    const float* __restrict__ bn1_g, const float* __restrict__ bn1_b,
    const float* __restrict__ bn1_m, const float* __restrict__ bn1_v,
    const float* __restrict__ conv_s_w, const float* __restrict__ conv_s_b,
    const float* __restrict__ bn2_g, const float* __restrict__ bn2_b,
    const float* __restrict__ bn2_m, const float* __restrict__ bn2_v,
    const float* __restrict__ proj_w, const float* __restrict__ proj_b,
    const float* __restrict__ cls_token, const float* __restrict__ pe,
    const float* __restrict__ qkv_w, const float* __restrict__ qkv_b,
    const float* __restrict__ out_w, const float* __restrict__ out_b,
    const float* __restrict__ ln1_g, const float* __restrict__ ln1_b,
    const float* __restrict__ ln2_g, const float* __restrict__ ln2_b,
    const float* __restrict__ mlp_w1, const float* __restrict__ mlp_b1,
    const float* __restrict__ mlp_w2, const float* __restrict__ mlp_b2,
    const float* __restrict__ head_ln_g, const float* __restrict__ head_ln_b,
    const float* __restrict__ head_w, const float* __restrict__ head_b,
    float* __restrict__ out)
{
    __shared__ __align__(16) float sm[LDS_TOT];
    const int b   = blockIdx.x;
    const int tid = threadIdx.x;

    // ---------- zero ONLY the pad zones of XSP: per row [0,32) and [157,196) ----
    // Disjoint from stage-1's store region [32,157) -> no cross-wave race.
    for (int i = tid; i < 16 * 71; i += TB) {
        int row = i / 71, k = i - row * 71;
        int off = (k < 32) ? k : (k + 125);            // 157 + (k-32)
        sm[XSP + row * 196 + off] = 0.f;
    }

    // ---------- stage 1: spatial conv, one t-column per lane ----------
    // xs[o][t] = sum_c ws[o][c] * x[c][t]
    {
        const float* xb = x + (size_t)b * 8000;
        const int t = min(tid, 124);
        float a0[16];
        #pragma unroll
        for (int o = 0; o < 16; ++o) a0[o] = 0.f;
        #pragma unroll 8
        for (int c = 0; c < 64; ++c) {
            float xv = xb[c * 125 + t];
            #pragma unroll
            for (int o = 0; o < 16; ++o)
                a0[o] += conv_s_w[o * 64 + c] * xv;    // wave-uniform -> s_load
        }
        if (tid < 125) {
            #pragma unroll
            for (int o = 0; o < 16; ++o)
                sm[XSP + o * 196 + 32 + t] = a0[o];
        }
    }

    // ---------- fused BN constants + temporal taps (per-lane, oo = tid&15) ------
    const int oo = tid & 15, qg = tid >> 4, gg = oo >> 1;   // qg in 0..7
    float sa, cc;
    {
        float s1 = bn1_g[gg] * rsqrtf(bn1_v[gg] + 1e-5f);
        float b1 = (conv_t_b[gg] - bn1_m[gg]) * s1 + bn1_b[gg];
        float s2 = bn2_g[oo] * rsqrtf(bn2_v[oo] + 1e-5f);
        float ssum = 0.f;
        const float4* csw = reinterpret_cast<const float4*>(conv_s_w + oo * 64);
        #pragma unroll
        for (int i = 0; i < 16; ++i) {
            float4 v = csw[i];
            ssum += v.x + v.y + v.z + v.w;
        }
        sa = s1 * s2;
        cc = (b1 * ssum + conv_s_b[oo] - bn2_m[oo]) * s2 + bn2_b[oo];
    }
    float wt[63];
    #pragma unroll
    for (int k = 0; k < 63; ++k) wt[k] = conv_t_w[gg * 63 + k];

    __syncthreads();   // XSP complete (cross-wave)

    // ---------- stage 2: temporal conv + BN + ELU + avg-pool ----------
    // lane (oo,qg) produces pooled[oo][j], j = qg + 8*jj (25 outputs/channel)
    #pragma unroll 1
    for (int jj = 0; jj < 4; ++jj) {
        int j = qg + 8 * jj;
        if (j < 25) {
            int base = XSP + oo * 196 + 5 * j + 1;
            float acc5[5] = {0.f, 0.f, 0.f, 0.f, 0.f};
            #pragma unroll
            for (int m = 0; m < 67; ++m) {
                float xv = sm[base + m];
                #pragma unroll
                for (int u = 0; u < 5; ++u)
                    if (u <= m && m - u <= 62) acc5[u] += wt[m - u] * xv;
            }
            float psum = 0.f;
            #pragma unroll
            for (int u = 0; u < 5; ++u) {
                float v = acc5[u] * sa + cc;
                psum += (v > 0.f) ? v : (__expf(v) - 1.f);
            }
            sm[POOL + oo * 28 + j] = psum * 0.2f;
        }
    }

    __syncthreads();   // POOL complete (cross-wave)

    // ---------- stage 3: token projection (5,80)@(80,16)^T, one out per lane ----
    if (tid < 80) {
        int p = tid >> 4, dd = tid & 15;
        float acc = proj_b[dd];
        const float4* wp = reinterpret_cast<const float4*>(proj_w + dd * 80);
        #pragma unroll
        for (int i = 0; i < 20; ++i) {
            float4 w4 = wp[i];
            acc += w4.x * sm[POOL + ((4*i+0)/5) * 28 + p * 5 + ((4*i+0)%5)];
            acc += w4.y * sm[POOL + ((4*i+1)/5) * 28 + p * 5 + ((4*i+1)%5)];
            acc += w4.z * sm[POOL + ((4*i+2)/5) * 28 + p * 5 + ((4*i+2)%5)];
            acc += w4.w * sm[POOL + ((4*i+3)/5) * 28 + p * 5 + ((4*i+3)%5)];
        }
        sm[TOK + p * 16 + dd] = acc;
    }

    __syncthreads();   // TOK complete (cross-wave)

    // ---------- z init: group t6 = tid>>4 owns one token; groups 6,7 mirror 5 ---
    const int d16 = tid & 15;
    const int t6c = min(tid >> 4, 5);          // groups 6,7 duplicate token 5
    float z = ((t6c == 0) ? cls_token[d16] : sm[TOK + (t6c - 1) * 16 + d16])
            + pe[t6c * 16 + d16];

    // ---------- transformer: 6 layers, 2 barriers per layer ----------
    #pragma unroll 1
    for (int li = 0; li < 6; ++li) {
        const float* qw  = qkv_w  + li * 3072;
        const float* qb2 = qkv_b  + li * 192;
        const float* ow  = out_w  + li * 1024;
        const float* w1  = mlp_w1 + li * 512;
        const float* w2  = mlp_w2 + li * 512;

        // --- LN1 -> H1 (group-local: same wave writes & reads its row) ---
        sm[H1 + t6c * 20 + d16] = ln_norm16(z, ln1_g[li * 16 + d16],
                                               ln1_b[li * 16 + d16]);
        WAVE_SYNC();

        float hr[16];
        {
            const float4* pA = reinterpret_cast<const float4*>(&sm[H1 + t6c * 20]);
            #pragma unroll
            for (int i = 0; i < 4; ++i) {
                float4 va = pA[i];
                hr[4*i+0] = va.x; hr[4*i+1] = va.y; hr[4*i+2] = va.z; hr[4*i+3] = va.w;
            }
        }

        // --- qkv: lane computes cols j = d16+16r for its token ---
        #pragma unroll 2
        for (int r = 0; r < 12; ++r) {
            int j = d16 + 16 * r;
            const float4* wp = reinterpret_cast<const float4*>(qw + j * 16);
            float4 w0 = wp[0], w1_ = wp[1], w2_ = wp[2], w3_ = wp[3];
            sm[QKV + t6c * 196 + j] = qb2[j] + dot16(hr, w0, w1_, w2_, w3_);
        }
        __syncthreads();   // QKV complete (attention reads all tokens, wave 0)

        // --- attention: lane = (head h, query s), 48 lanes of wave 0 ---
        if (tid < 48) {
            int h = tid & 7, s = tid >> 3;
            const float4* qp = reinterpret_cast<const float4*>(&sm[QKV + s * 196 + h * 8]);
            float4 q0 = qp[0], q1 = qp[1];
            float sc[6];
            #pragma unroll
            for (int u = 0; u < 6; ++u) {
                const float4* kp = reinterpret_cast<const float4*>(&sm[QKV + u * 196 + 64 + h * 8]);
                float4 k0 = kp[0], k1 = kp[1];
                sc[u] = (q0.x*k0.x + q0.y*k0.y + q0.z*k0.z + q0.w*k0.w
                       + q1.x*k1.x + q1.y*k1.y + q1.z*k1.z + q1.w*k1.w)
                       * 0.35355339059327373f;
            }
            float mx = sc[0];
            #pragma unroll
            for (int u = 1; u < 6; ++u) mx = fmaxf(mx, sc[u]);
            float ssum = 0.f;
            #pragma unroll
            for (int u = 0; u < 6; ++u) { sc[u] = __expf(sc[u] - mx); ssum += sc[u]; }
            float inv = 1.f / ssum;
            float o0 = 0.f, o1 = 0.f, o2 = 0.f, o3 = 0.f,
                  o4 = 0.f, o5 = 0.f, o6 = 0.f, o7 = 0.f;
            #pragma unroll
            for (int u = 0; u < 6; ++u) {
                const float4* vp = reinterpret_cast<const float4*>(&sm[QKV + u * 196 + 128 + h * 8]);
                float4 v0 = vp[0], v1 = vp[1];
                float a = sc[u] * inv;
                o0 += a * v0.x; o1 += a * v0.y; o2 += a * v0.z; o3 += a * v0.w;
                o4 += a * v1.x; o5 += a * v1.y; o6 += a * v1.z; o7 += a * v1.w;
            }
            *reinterpret_cast<float4*>(&sm[OATT + s * 68 + h * 8    ]) = float4{o0, o1, o2, o3};
            *reinterpret_cast<float4*>(&sm[OATT + s * 68 + h * 8 + 4]) = float4{o4, o5, o6, o7};
        }
        __syncthreads();   // OATT complete (all lanes read)

        // --- out projection + residual ---
        {
            const float4* wop = reinterpret_cast<const float4*>(ow + d16 * 64);
            const float4* oa  = reinterpret_cast<const float4*>(&sm[OATT + t6c * 68]);
            float acc = out_b[li * 16 + d16];
            #pragma unroll 4
            for (int i = 0; i < 16; ++i) {
                float4 w = wop[i];
                float4 va = oa[i];
                acc += va.x*w.x + va.y*w.y + va.z*w.z + va.w*w.w;
            }
            z += acc;
        }

        // --- LN2 -> H1 (group-local) ---
        sm[H1 + t6c * 20 + d16] = ln_norm16(z, ln2_g[li * 16 + d16],
                                               ln2_b[li * 16 + d16]);
        WAVE_SYNC();
        {
            const float4* pA = reinterpret_cast<const float4*>(&sm[H1 + t6c * 20]);
            #pragma unroll
            for (int i = 0; i < 4; ++i) {
                float4 va = pA[i];
                hr[4*i+0] = va.x; hr[4*i+1] = va.y; hr[4*i+2] = va.z; hr[4*i+3] = va.w;
            }
        }

        // --- mlp1 + GELU -> MHS (group-local) ---
        #pragma unroll
        for (int r = 0; r < 2; ++r) {
            int u = d16 + 16 * r;
            const float4* wp = reinterpret_cast<const float4*>(w1 + u * 16);
            float4 w0 = wp[0], w1_ = wp[1], w2_ = wp[2], w3_ = wp[3];
            float a = mlp_b1[li * 32 + u] + dot16(hr, w0, w1_, w2_, w3_);
            sm[MHS + t6c * 36 + u] = gelu_exact(a);
        }
        WAVE_SYNC();

        // --- mlp2 + residual (group-local MHS read) ---
        {
            const float4* wp = reinterpret_cast<const float4*>(w2 + d16 * 32);
            const float4* mA = reinterpret_cast<const float4*>(&sm[MHS + t6c * 36]);
            float acc = mlp_b2[li * 16 + d16];
            #pragma unroll
            for (int i = 0; i < 8; ++i) {
                float4 w = wp[i];
                float4 va = mA[i];
                acc += va.x*w.x + va.y*w.y + va.z*w.z + va.w*w.w;
            }
            z += acc;
        }
        WAVE_SYNC();   // keep same-wave H1/MHS ordering into next layer
    }

    // ---------- head: LN(cls) -> 2-way linear -> softmax ----------
    if (tid < 16) {
        float cv = ln_norm16(z, head_ln_g[d16], head_ln_b[d16]);
        float p0 = cv * head_w[d16];
        float p1 = cv * head_w[16 + d16];
        #pragma unroll
        for (int off = 8; off >= 1; off >>= 1) {
            p0 += __shfl_xor(p0, off, 16);
            p1 += __shfl_xor(p1, off, 16);
        }
        if (tid == 0) {
            float l0 = p0 + head_b[0], l1 = p1 + head_b[1];
            float mx = fmaxf(l0, l1);
            float e0 = __expf(l0 - mx), e1 = __expf(l1 - mx);
            float inv = 1.f / (e0 + e1);
            out[b * 2 + 0] = e0 * inv;
            out[b * 2 + 1] = e1 * inv;
        }
    }
}

extern "C" void kernel_launch(void* const* d_in, const int* in_sizes, int n_in,
                              void* d_out, int out_size, void* d_ws, size_t ws_size,
                              hipStream_t stream) {
    (void)n_in; (void)d_ws; (void)ws_size; (void)out_size;
    const float* a0  = (const float*)d_in[0];
    const float* a1  = (const float*)d_in[1];
    const float* a2  = (const float*)d_in[2];
    const float* a3  = (const float*)d_in[3];
    const float* a4  = (const float*)d_in[4];
    const float* a5  = (const float*)d_in[5];
    const float* a6  = (const float*)d_in[6];
    const float* a7  = (const float*)d_in[7];
    const float* a8  = (const float*)d_in[8];
    const float* a9  = (const float*)d_in[9];
    const float* a10 = (const float*)d_in[10];
    const float* a11 = (const float*)d_in[11];
    const float* a12 = (const float*)d_in[12];
    const float* a13 = (const float*)d_in[13];
    const float* a14 = (const float*)d_in[14];
    const float* a15 = (const float*)d_in[15];
    const float* a16 = (const float*)d_in[16];
    const float* a17 = (const float*)d_in[17];
    const float* a18 = (const float*)d_in[18];
    const float* a19 = (const float*)d_in[19];
    const float* a20 = (const float*)d_in[20];
    const float* a21 = (const float*)d_in[21];
    const float* a22 = (const float*)d_in[22];
    const float* a23 = (const float*)d_in[23];
    const float* a24 = (const float*)d_in[24];
    const float* a25 = (const float*)d_in[25];
    const float* a26 = (const float*)d_in[26];
    const float* a27 = (const float*)d_in[27];
    const float* a28 = (const float*)d_in[28];
    const float* a29 = (const float*)d_in[29];
    const float* a30 = (const float*)d_in[30];
    const float* a31 = (const float*)d_in[31];
    const float* a32 = (const float*)d_in[32];

    int Bn = in_sizes[0] / (64 * 125);          // 2048 samples, 2 waves each
    eegnet_vit_fused<<<Bn, TB, 0, stream>>>(
        a0, a1, a2, a3, a4, a5, a6, a7, a8, a9, a10, a11, a12, a13, a14, a15, a16,
        a17, a18, a19, a20, a21, a22, a23, a24, a25, a26, a27, a28, a29, a30, a31, a32,
        (float*)d_out);
}

// Round 4
// 327.012 us; speedup vs baseline: 1.2503x; 1.2503x over previous
//
#include <hip/hip_runtime.h>

#define TB 128

// Wave-synchronous fence: DS ops complete in order within a wave (ISA
// guarantee); this only stops the COMPILER from reordering/caching LDS.
#define WAVE_SYNC() do { asm volatile("" ::: "memory"); \
                         __builtin_amdgcn_wave_barrier(); \
                         asm volatile("" ::: "memory"); } while (0)

// ---------------- LDS layout (float offsets), total 3664 floats = 14.3 KB ----
#define XSP    0        // 16 rows x 196 (spatial-conv out, zero-padded both sides)
// transformer scratch aliases XSP (frontend dead by then):
#define H1     0        // 6 x 20
#define QKV    128      // 6 x 196 (q at +0, k at +64, v at +128 within row)
#define OATT   1312     // 6 x 68
#define MHS    1728     // 6 x 36   (ends 1944 < 3136)
#define POOL   3136     // 16 x 28
#define TOK    3584     // 80
#define LDS_TOT 3664

__device__ __forceinline__ float ln_norm16(float z, float g, float bb) {
    float s = z, q = z * z;
    #pragma unroll
    for (int off = 8; off >= 1; off >>= 1) {
        s += __shfl_xor(s, off, 16);
        q += __shfl_xor(q, off, 16);
    }
    float mean = s * 0.0625f;
    float var  = q * 0.0625f - mean * mean;
    return (z - mean) * rsqrtf(var + 1e-5f) * g + bb;
}

__device__ __forceinline__ float gelu_exact(float a) {
    float xa = fabsf(a) * 0.70710678118654752f;
    float tt = 1.f / (1.f + 0.3275911f * xa);
    float poly = tt * (0.254829592f + tt * (-0.284496736f + tt * (1.421413741f
               + tt * (-1.453152027f + tt * 1.061405429f))));
    float erfv = 1.f - poly * __expf(-xa * xa);
    erfv = a >= 0.f ? erfv : -erfv;
    return 0.5f * a * (1.f + erfv);
}

__device__ __forceinline__ float dot16(const float* h, float4 w0, float4 w1,
                                       float4 w2, float4 w3) {
    return h[0]*w0.x + h[1]*w0.y + h[2]*w0.z + h[3]*w0.w
         + h[4]*w1.x + h[5]*w1.y + h[6]*w1.z + h[7]*w1.w
         + h[8]*w2.x + h[9]*w2.y + h[10]*w2.z + h[11]*w2.w
         + h[12]*w3.x + h[13]*w3.y + h[14]*w3.z + h[15]*w3.w;
}

// launch_bounds(128, 2): VGPR cap 256. Round 3's (128,4) forced a 64-VGPR
// budget -> wt[63] spilled to scratch -> 141 MB WRITE_SIZE, 2.5x regression.
// This structure fits in ~128 VGPRs (round 2 evidence), which still allows
// 4 waves/SIMD = 16 waves/CU = all 8 blocks/CU resident.
extern "C" __global__ __launch_bounds__(TB, 2)
void eegnet_vit_fused(
    const float* __restrict__ x,
    const float* __restrict__ conv_t_w, const float* __restrict__ conv_t_b,
    const float* __restrict__ bn1_g, const float* __restrict__ bn1_b,
    const float* __restrict__ bn1_m, const float* __restrict__ bn1_v,
    const float* __restrict__ conv_s_w, const float* __restrict__ conv_s_b,
    const float* __restrict__ bn2_g, const float* __restrict__ bn2_b,
    const float* __restrict__ bn2_m, const float* __restrict__ bn2_v,
    const float* __restrict__ proj_w, const float* __restrict__ proj_b,
    const float* __restrict__ cls_token, const float* __restrict__ pe,
    const float* __restrict__ qkv_w, const float* __restrict__ qkv_b,
    const float* __restrict__ out_w, const float* __restrict__ out_b,
    const float* __restrict__ ln1_g, const float* __restrict__ ln1_b,
    const float* __restrict__ ln2_g, const float* __restrict__ ln2_b,
    const float* __restrict__ mlp_w1, const float* __restrict__ mlp_b1,
    const float* __restrict__ mlp_w2, const float* __restrict__ mlp_b2,
    const float* __restrict__ head_ln_g, const float* __restrict__ head_ln_b,
    const float* __restrict__ head_w, const float* __restrict__ head_b,
    float* __restrict__ out)
{
    __shared__ __align__(16) float sm[LDS_TOT];
    const int b   = blockIdx.x;
    const int tid = threadIdx.x;

    // ---------- zero ONLY the pad zones of XSP: per row [0,32) and [157,196) ----
    // Disjoint from stage-1's store region [32,157) -> no cross-wave race.
    for (int i = tid; i < 16 * 71; i += TB) {
        int row = i / 71, k = i - row * 71;
        int off = (k < 32) ? k : (k + 125);            // 157 + (k-32)
        sm[XSP + row * 196 + off] = 0.f;
    }

    // ---------- stage 1: spatial conv, one t-column per lane ----------
    // xs[o][t] = sum_c ws[o][c] * x[c][t]
    {
        const float* xb = x + (size_t)b * 8000;
        const int t = min(tid, 124);
        float a0[16];
        #pragma unroll
        for (int o = 0; o < 16; ++o) a0[o] = 0.f;
        #pragma unroll 8
        for (int c = 0; c < 64; ++c) {
            float xv = xb[c * 125 + t];
            #pragma unroll
            for (int o = 0; o < 16; ++o)
                a0[o] += conv_s_w[o * 64 + c] * xv;    // wave-uniform -> s_load
        }
        if (tid < 125) {
            #pragma unroll
            for (int o = 0; o < 16; ++o)
                sm[XSP + o * 196 + 32 + t] = a0[o];
        }
    }

    // ---------- fused BN constants + temporal taps (per-lane, oo = tid&15) ------
    const int oo = tid & 15, qg = tid >> 4, gg = oo >> 1;   // qg in 0..7
    float sa, cc;
    {
        float s1 = bn1_g[gg] * rsqrtf(bn1_v[gg] + 1e-5f);
        float b1 = (conv_t_b[gg] - bn1_m[gg]) * s1 + bn1_b[gg];
        float s2 = bn2_g[oo] * rsqrtf(bn2_v[oo] + 1e-5f);
        float ssum = 0.f;
        const float4* csw = reinterpret_cast<const float4*>(conv_s_w + oo * 64);
        #pragma unroll
        for (int i = 0; i < 16; ++i) {
            float4 v = csw[i];
            ssum += v.x + v.y + v.z + v.w;
        }
        sa = s1 * s2;
        cc = (b1 * ssum + conv_s_b[oo] - bn2_m[oo]) * s2 + bn2_b[oo];
    }
    float wt[63];
    #pragma unroll
    for (int k = 0; k < 63; ++k) wt[k] = conv_t_w[gg * 63 + k];

    __syncthreads();   // XSP complete (cross-wave)

    // ---------- stage 2: temporal conv + BN + ELU + avg-pool ----------
    // lane (oo,qg) produces pooled[oo][j], j = qg + 8*jj (25 outputs/channel)
    #pragma unroll 1
    for (int jj = 0; jj < 4; ++jj) {
        int j = qg + 8 * jj;
        if (j < 25) {
            int base = XSP + oo * 196 + 5 * j + 1;
            float acc5[5] = {0.f, 0.f, 0.f, 0.f, 0.f};
            #pragma unroll
            for (int m = 0; m < 67; ++m) {
                float xv = sm[base + m];
                #pragma unroll
                for (int u = 0; u < 5; ++u)
                    if (u <= m && m - u <= 62) acc5[u] += wt[m - u] * xv;
            }
            float psum = 0.f;
            #pragma unroll
            for (int u = 0; u < 5; ++u) {
                float v = acc5[u] * sa + cc;
                psum += (v > 0.f) ? v : (__expf(v) - 1.f);
            }
            sm[POOL + oo * 28 + j] = psum * 0.2f;
        }
    }

    __syncthreads();   // POOL complete (cross-wave)

    // ---------- stage 3: token projection (5,80)@(80,16)^T, one out per lane ----
    if (tid < 80) {
        int p = tid >> 4, dd = tid & 15;
        float acc = proj_b[dd];
        const float4* wp = reinterpret_cast<const float4*>(proj_w + dd * 80);
        #pragma unroll
        for (int i = 0; i < 20; ++i) {
            float4 w4 = wp[i];
            acc += w4.x * sm[POOL + ((4*i+0)/5) * 28 + p * 5 + ((4*i+0)%5)];
            acc += w4.y * sm[POOL + ((4*i+1)/5) * 28 + p * 5 + ((4*i+1)%5)];
            acc += w4.z * sm[POOL + ((4*i+2)/5) * 28 + p * 5 + ((4*i+2)%5)];
            acc += w4.w * sm[POOL + ((4*i+3)/5) * 28 + p * 5 + ((4*i+3)%5)];
        }
        sm[TOK + p * 16 + dd] = acc;
    }

    __syncthreads();   // TOK complete (cross-wave)

    // ---------- z init: group t6 = tid>>4 owns one token; groups 6,7 mirror 5 ---
    const int d16 = tid & 15;
    const int t6c = min(tid >> 4, 5);          // groups 6,7 duplicate token 5
    float z = ((t6c == 0) ? cls_token[d16] : sm[TOK + (t6c - 1) * 16 + d16])
            + pe[t6c * 16 + d16];

    // ---------- transformer: 6 layers, 2 barriers per layer ----------
    #pragma unroll 1
    for (int li = 0; li < 6; ++li) {
        const float* qw  = qkv_w  + li * 3072;
        const float* qb2 = qkv_b  + li * 192;
        const float* ow  = out_w  + li * 1024;
        const float* w1  = mlp_w1 + li * 512;
        const float* w2  = mlp_w2 + li * 512;

        // --- LN1 -> H1 (group-local: same wave writes & reads its row) ---
        sm[H1 + t6c * 20 + d16] = ln_norm16(z, ln1_g[li * 16 + d16],
                                               ln1_b[li * 16 + d16]);
        WAVE_SYNC();

        float hr[16];
        {
            const float4* pA = reinterpret_cast<const float4*>(&sm[H1 + t6c * 20]);
            #pragma unroll
            for (int i = 0; i < 4; ++i) {
                float4 va = pA[i];
                hr[4*i+0] = va.x; hr[4*i+1] = va.y; hr[4*i+2] = va.z; hr[4*i+3] = va.w;
            }
        }

        // --- qkv: lane computes cols j = d16+16r for its token ---
        #pragma unroll 2
        for (int r = 0; r < 12; ++r) {
            int j = d16 + 16 * r;
            const float4* wp = reinterpret_cast<const float4*>(qw + j * 16);
            float4 w0 = wp[0], w1_ = wp[1], w2_ = wp[2], w3_ = wp[3];
            sm[QKV + t6c * 196 + j] = qb2[j] + dot16(hr, w0, w1_, w2_, w3_);
        }
        __syncthreads();   // QKV complete (attention reads all tokens, wave 0)

        // --- attention: lane = (head h, query s), 48 lanes of wave 0 ---
        if (tid < 48) {
            int h = tid & 7, s = tid >> 3;
            const float4* qp = reinterpret_cast<const float4*>(&sm[QKV + s * 196 + h * 8]);
            float4 q0 = qp[0], q1 = qp[1];
            float sc[6];
            #pragma unroll
            for (int u = 0; u < 6; ++u) {
                const float4* kp = reinterpret_cast<const float4*>(&sm[QKV + u * 196 + 64 + h * 8]);
                float4 k0 = kp[0], k1 = kp[1];
                sc[u] = (q0.x*k0.x + q0.y*k0.y + q0.z*k0.z + q0.w*k0.w
                       + q1.x*k1.x + q1.y*k1.y + q1.z*k1.z + q1.w*k1.w)
                       * 0.35355339059327373f;
            }
            float mx = sc[0];
            #pragma unroll
            for (int u = 1; u < 6; ++u) mx = fmaxf(mx, sc[u]);
            float ssum = 0.f;
            #pragma unroll
            for (int u = 0; u < 6; ++u) { sc[u] = __expf(sc[u] - mx); ssum += sc[u]; }
            float inv = 1.f / ssum;
            float o0 = 0.f, o1 = 0.f, o2 = 0.f, o3 = 0.f,
                  o4 = 0.f, o5 = 0.f, o6 = 0.f, o7 = 0.f;
            #pragma unroll
            for (int u = 0; u < 6; ++u) {
                const float4* vp = reinterpret_cast<const float4*>(&sm[QKV + u * 196 + 128 + h * 8]);
                float4 v0 = vp[0], v1 = vp[1];
                float a = sc[u] * inv;
                o0 += a * v0.x; o1 += a * v0.y; o2 += a * v0.z; o3 += a * v0.w;
                o4 += a * v1.x; o5 += a * v1.y; o6 += a * v1.z; o7 += a * v1.w;
            }
            *reinterpret_cast<float4*>(&sm[OATT + s * 68 + h * 8    ]) = float4{o0, o1, o2, o3};
            *reinterpret_cast<float4*>(&sm[OATT + s * 68 + h * 8 + 4]) = float4{o4, o5, o6, o7};
        }
        __syncthreads();   // OATT complete (all lanes read)

        // --- out projection + residual ---
        {
            const float4* wop = reinterpret_cast<const float4*>(ow + d16 * 64);
            const float4* oa  = reinterpret_cast<const float4*>(&sm[OATT + t6c * 68]);
            float acc = out_b[li * 16 + d16];
            #pragma unroll 4
            for (int i = 0; i < 16; ++i) {
                float4 w = wop[i];
                float4 va = oa[i];
                acc += va.x*w.x + va.y*w.y + va.z*w.z + va.w*w.w;
            }
            z += acc;
        }

        // --- LN2 -> H1 (group-local) ---
        sm[H1 + t6c * 20 + d16] = ln_norm16(z, ln2_g[li * 16 + d16],
                                               ln2_b[li * 16 + d16]);
        WAVE_SYNC();
        {
            const float4* pA = reinterpret_cast<const float4*>(&sm[H1 + t6c * 20]);
            #pragma unroll
            for (int i = 0; i < 4; ++i) {
                float4 va = pA[i];
                hr[4*i+0] = va.x; hr[4*i+1] = va.y; hr[4*i+2] = va.z; hr[4*i+3] = va.w;
            }
        }

        // --- mlp1 + GELU -> MHS (group-local) ---
        #pragma unroll
        for (int r = 0; r < 2; ++r) {
            int u = d16 + 16 * r;
            const float4* wp = reinterpret_cast<const float4*>(w1 + u * 16);
            float4 w0 = wp[0], w1_ = wp[1], w2_ = wp[2], w3_ = wp[3];
            float a = mlp_b1[li * 32 + u] + dot16(hr, w0, w1_, w2_, w3_);
            sm[MHS + t6c * 36 + u] = gelu_exact(a);
        }
        WAVE_SYNC();

        // --- mlp2 + residual (group-local MHS read) ---
        {
            const float4* wp = reinterpret_cast<const float4*>(w2 + d16 * 32);
            const float4* mA = reinterpret_cast<const float4*>(&sm[MHS + t6c * 36]);
            float acc = mlp_b2[li * 16 + d16];
            #pragma unroll
            for (int i = 0; i < 8; ++i) {
                float4 w = wp[i];
                float4 va = mA[i];
                acc += va.x*w.x + va.y*w.y + va.z*w.z + va.w*w.w;
            }
            z += acc;
        }
        WAVE_SYNC();   // keep same-wave H1/MHS ordering into next layer
    }

    // ---------- head: LN(cls) -> 2-way linear -> softmax ----------
    if (tid < 16) {
        float cv = ln_norm16(z, head_ln_g[d16], head_ln_b[d16]);
        float p0 = cv * head_w[d16];
        float p1 = cv * head_w[16 + d16];
        #pragma unroll
        for (int off = 8; off >= 1; off >>= 1) {
            p0 += __shfl_xor(p0, off, 16);
            p1 += __shfl_xor(p1, off, 16);
        }
        if (tid == 0) {
            float l0 = p0 + head_b[0], l1 = p1 + head_b[1];
            float mx = fmaxf(l0, l1);
            float e0 = __expf(l0 - mx), e1 = __expf(l1 - mx);
            float inv = 1.f / (e0 + e1);
            out[b * 2 + 0] = e0 * inv;
            out[b * 2 + 1] = e1 * inv;
        }
    }
}

extern "C" void kernel_launch(void* const* d_in, const int* in_sizes, int n_in,
                              void* d_out, int out_size, void* d_ws, size_t ws_size,
                              hipStream_t stream) {
    (void)n_in; (void)d_ws; (void)ws_size; (void)out_size;
    const float* a0  = (const float*)d_in[0];
    const float* a1  = (const float*)d_in[1];
    const float* a2  = (const float*)d_in[2];
    const float* a3  = (const float*)d_in[3];
    const float* a4  = (const float*)d_in[4];
    const float* a5  = (const float*)d_in[5];
    const float* a6  = (const float*)d_in[6];
    const float* a7  = (const float*)d_in[7];
    const float* a8  = (const float*)d_in[8];
    const float* a9  = (const float*)d_in[9];
    const float* a10 = (const float*)d_in[10];
    const float* a11 = (const float*)d_in[11];
    const float* a12 = (const float*)d_in[12];
    const float* a13 = (const float*)d_in[13];
    const float* a14 = (const float*)d_in[14];
    const float* a15 = (const float*)d_in[15];
    const float* a16 = (const float*)d_in[16];
    const float* a17 = (const float*)d_in[17];
    const float* a18 = (const float*)d_in[18];
    const float* a19 = (const float*)d_in[19];
    const float* a20 = (const float*)d_in[20];
    const float* a21 = (const float*)d_in[21];
    const float* a22 = (const float*)d_in[22];
    const float* a23 = (const float*)d_in[23];
    const float* a24 = (const float*)d_in[24];
    const float* a25 = (const float*)d_in[25];
    const float* a26 = (const float*)d_in[26];
    const float* a27 = (const float*)d_in[27];
    const float* a28 = (const float*)d_in[28];
    const float* a29 = (const float*)d_in[29];
    const float* a30 = (const float*)d_in[30];
    const float* a31 = (const float*)d_in[31];
    const float* a32 = (const float*)d_in[32];

    int Bn = in_sizes[0] / (64 * 125);          // 2048 samples, 2 waves each
    eegnet_vit_fused<<<Bn, TB, 0, stream>>>(
        a0, a1, a2, a3, a4, a5, a6, a7, a8, a9, a10, a11, a12, a13, a14, a15, a16,
        a17, a18, a19, a20, a21, a22, a23, a24, a25, a26, a27, a28, a29, a30, a31, a32,
        (float*)d_out);
}